// Round 5
// baseline (175.938 us; speedup 1.0000x reference)
//
#include <hip/hip_runtime.h>
#include <math.h>

#define N_ 2
#define L_ 2048
#define S_ 2048
#define H_ 8
#define D_ 64

#define BLK_L 256        // l-rows per block (4 waves x 64)
#define BS 64            // s-rows per K tile
#define SSPLIT 8
#define TILES (S_ / SSPLIT / BS)   // 4
#define KROW 80          // LDS row stride in shorts (160B): 0 bank conflicts (R4 measured)
#define KP 32            // ksum partial slices (S/64)

typedef __attribute__((ext_vector_type(8))) short short8;
typedef __attribute__((ext_vector_type(4))) float floatx4;

__device__ __forceinline__ float feat(float x) {
    // elu(x)+1 = x>0 ? x+1 : exp(x)
    return x > 0.0f ? x + 1.0f : __expf(x);
}
__device__ __forceinline__ short f2bf(float x) {
    unsigned u = __float_as_uint(x);
    unsigned r = (u + 0x7fffu + ((u >> 16) & 1u)) >> 16;   // round-nearest-even
    return (short)r;
}
__device__ __forceinline__ float bf2f(short h) {
    return __uint_as_float(((unsigned)(unsigned short)h) << 16);
}

// ---- K feature-sum partials (no atomics, no memset) ----
__global__ __launch_bounds__(256) void ksum_kernel(const float* __restrict__ K,
        const float* __restrict__ kvmask, float* __restrict__ Kpart) {
    int nh = blockIdx.x;          // 16
    int sc = blockIdx.y;          // 32 chunks of 64 s-rows
    int n = nh >> 3, h = nh & 7;
    int t = threadIdx.x;
    int sr = t >> 4;              // 0..15
    int d4 = (t & 15) * 4;
    float sums[4] = {0.f, 0.f, 0.f, 0.f};
    #pragma unroll
    for (int p = 0; p < 4; ++p) {
        int s = sc * 64 + p * 16 + sr;
        float km = kvmask[n * S_ + s];
        float4 v = *(const float4*)(K + (((size_t)n * S_ + s) * H_ + h) * D_ + d4);
        sums[0] += feat(v.x) * km; sums[1] += feat(v.y) * km;
        sums[2] += feat(v.z) * km; sums[3] += feat(v.w) * km;
    }
    __shared__ float smf[16][64];
    #pragma unroll
    for (int j = 0; j < 4; ++j) smf[sr][d4 + j] = sums[j];
    __syncthreads();
    if (t < 64) {
        float s = 0.f;
        #pragma unroll
        for (int r = 0; r < 16; ++r) s += smf[r][t];
        Kpart[(sc * 16 + nh) * 64 + t] = s;
    }
}

// ---- fused row-max: featurize K in-kernel, compensated-bf16 MFMA ----
__global__ __launch_bounds__(256, 4) void rowmax_mfma(
        const float* __restrict__ Q, const float* __restrict__ K,
        const float* __restrict__ qmask, const float* __restrict__ kvmask,
        float* __restrict__ rowpart) {
    __shared__ short Kh[2][BS * KROW];
    __shared__ short Kl[2][BS * KROW];

    // XCD swizzle: blocks sharing a K slice (same nh,z; all 8 ltiles) have ids
    // differing by 128 == 0 mod 8 -> same XCD -> K slice lives in one L2.
    int bid = blockIdx.x;
    int ltile = bid >> 7;         // 0..7
    int rem = bid & 127;
    int nh = rem >> 3;            // 0..15
    int z = rem & 7;              // 0..7
    int n = nh >> 3, h = nh & 7;
    int t = threadIdx.x;
    int w = t >> 6, lane = t & 63;
    int quad = lane >> 4, l16 = lane & 15;
    int lblock = ltile * BLK_L;

    // ---- prologue: featurize Q -> A fragments in registers (hi/lo bf16) ----
    // A-frag layout (16x16x32): m = lane&15, k = quad*8 + j
    short8 Ah[4][2], Al[4][2];
    #pragma unroll
    for (int lsub = 0; lsub < 4; ++lsub) {
        int lrow = lblock + w * 64 + lsub * 16 + l16;
        float qm = qmask[n * L_ + lrow];
        const float* qp = Q + (((size_t)n * L_ + lrow) * H_ + h) * D_ + quad * 8;
        #pragma unroll
        for (int ks = 0; ks < 2; ++ks) {
            float4 v0 = *(const float4*)(qp + ks * 32);
            float4 v1 = *(const float4*)(qp + ks * 32 + 4);
            float fv[8];
            fv[0] = feat(v0.x) * qm; fv[1] = feat(v0.y) * qm;
            fv[2] = feat(v0.z) * qm; fv[3] = feat(v0.w) * qm;
            fv[4] = feat(v1.x) * qm; fv[5] = feat(v1.y) * qm;
            fv[6] = feat(v1.z) * qm; fv[7] = feat(v1.w) * qm;
            short8 hi, lo;
            #pragma unroll
            for (int j = 0; j < 8; ++j) {
                short hb = f2bf(fv[j]);
                hi[j] = hb;
                lo[j] = f2bf(fv[j] - bf2f(hb));
            }
            Ah[lsub][ks] = hi;
            Al[lsub][ks] = lo;
        }
    }

    // staging: thread -> (srow = t>>2, 16-float chunk = t&3)
    int srow = t >> 2, chunk = t & 3;
    float4 sv[4];
    float skm;

    auto loadreg = [&](int tile) {
        int sbase = z * (S_ / SSPLIT) + tile * BS;
        const float* kp = K + (((size_t)n * S_ + sbase + srow) * H_ + h) * D_ + chunk * 16;
        sv[0] = *(const float4*)(kp);
        sv[1] = *(const float4*)(kp + 4);
        sv[2] = *(const float4*)(kp + 8);
        sv[3] = *(const float4*)(kp + 12);
        skm = kvmask[n * S_ + sbase + srow];
    };
    auto featstore = [&](int buf) {
        float fv[16];
        #pragma unroll
        for (int j = 0; j < 4; ++j) {
            fv[4 * j + 0] = feat(sv[j].x) * skm;
            fv[4 * j + 1] = feat(sv[j].y) * skm;
            fv[4 * j + 2] = feat(sv[j].z) * skm;
            fv[4 * j + 3] = feat(sv[j].w) * skm;
        }
        short8 h0, h1, l0, l1;
        #pragma unroll
        for (int j = 0; j < 8; ++j) {
            short hb = f2bf(fv[j]);
            h0[j] = hb;
            l0[j] = f2bf(fv[j] - bf2f(hb));
            short hb2 = f2bf(fv[8 + j]);
            h1[j] = hb2;
            l1[j] = f2bf(fv[8 + j] - bf2f(hb2));
        }
        short* dh = &Kh[buf][srow * KROW + chunk * 16];
        short* dl = &Kl[buf][srow * KROW + chunk * 16];
        *(short8*)(dh)     = h0;
        *(short8*)(dh + 8) = h1;
        *(short8*)(dl)     = l0;
        *(short8*)(dl + 8) = l1;
    };

    float rmax[4][4];
    #pragma unroll
    for (int i = 0; i < 4; ++i)
        #pragma unroll
        for (int r = 0; r < 4; ++r) rmax[i][r] = 0.f;   // dots >= 0

    loadreg(0);
    featstore(0);
    __syncthreads();

    for (int tile = 0; tile < TILES; ++tile) {
        int cur = tile & 1;
        if (tile + 1 < TILES) loadreg(tile + 1);   // loads fly during MFMA

        #pragma unroll
        for (int ssub = 0; ssub < 4; ++ssub) {
            // B-frag: n = lane&15 (s-row), k = quad*8 + j
            const short* bph = &Kh[cur][(ssub * 16 + l16) * KROW + quad * 8];
            const short* bpl = &Kl[cur][(ssub * 16 + l16) * KROW + quad * 8];
            short8 Bh0 = *(const short8*)(bph);
            short8 Bh1 = *(const short8*)(bph + 32);
            short8 Bl0 = *(const short8*)(bpl);
            short8 Bl1 = *(const short8*)(bpl + 32);
            #pragma unroll
            for (int lsub = 0; lsub < 4; ++lsub) {
                floatx4 acc = {0.f, 0.f, 0.f, 0.f};
                acc = __builtin_amdgcn_mfma_f32_16x16x32_bf16(Ah[lsub][0], Bh0, acc, 0, 0, 0);
                acc = __builtin_amdgcn_mfma_f32_16x16x32_bf16(Ah[lsub][1], Bh1, acc, 0, 0, 0);
                acc = __builtin_amdgcn_mfma_f32_16x16x32_bf16(Ah[lsub][0], Bl0, acc, 0, 0, 0);
                acc = __builtin_amdgcn_mfma_f32_16x16x32_bf16(Ah[lsub][1], Bl1, acc, 0, 0, 0);
                acc = __builtin_amdgcn_mfma_f32_16x16x32_bf16(Al[lsub][0], Bh0, acc, 0, 0, 0);
                acc = __builtin_amdgcn_mfma_f32_16x16x32_bf16(Al[lsub][1], Bh1, acc, 0, 0, 0);
                #pragma unroll
                for (int r = 0; r < 4; ++r)
                    rmax[lsub][r] = fmaxf(rmax[lsub][r], acc[r]);
            }
        }

        if (tile + 1 < TILES) featstore(1 - cur);  // featurize overlaps MFMA pipes
        __syncthreads();
    }

    // ---- epilogue: reduce across 16 column-lanes, write z-partial ----
    // C/D layout: col(s) = lane&15, row(l) = quad*4 + r
    #pragma unroll
    for (int lsub = 0; lsub < 4; ++lsub)
        #pragma unroll
        for (int r = 0; r < 4; ++r) {
            float m = rmax[lsub][r];
            m = fmaxf(m, __shfl_xor(m, 1, 64));
            m = fmaxf(m, __shfl_xor(m, 2, 64));
            m = fmaxf(m, __shfl_xor(m, 4, 64));
            m = fmaxf(m, __shfl_xor(m, 8, 64));
            if (l16 == 0) {
                int l = lblock + w * 64 + lsub * 16 + quad * 4 + r;
                rowpart[((size_t)z * 16 + nh) * L_ + l] = m;
            }
        }
}

// ---- finalize: Ksum reduce + mean + max + gate + masked write ----
__global__ __launch_bounds__(256) void finalize_kernel(
        const float* __restrict__ Q, const float* __restrict__ qmask,
        const float* __restrict__ Kpart, const float* __restrict__ rowpart,
        const float* __restrict__ W, const float* __restrict__ b,
        float* __restrict__ out) {
    int nh = blockIdx.y;
    int n = nh >> 3, h = nh & 7;
    int lblock = blockIdx.x * 64;
    int t = threadIdx.x;
    int w = t >> 6, lane = t & 63;

    float ks = 0.f;
    #pragma unroll 8
    for (int p = 0; p < KP; ++p)
        ks += Kpart[(p * 16 + nh) * 64 + lane];

    float w0 = W[0], w1 = W[1], bb = b[0];

    #pragma unroll 4
    for (int r = 0; r < 16; ++r) {
        int l = lblock + w * 16 + r;
        float q = Q[(((size_t)n * L_ + l) * H_ + h) * D_ + lane];
        float qm = qmask[n * L_ + l];
        float p = feat(q) * qm * ks;
        #pragma unroll
        for (int off = 32; off > 0; off >>= 1)
            p += __shfl_xor(p, off, 64);
        float mx = 0.f;
        #pragma unroll
        for (int zz = 0; zz < SSPLIT; ++zz)
            mx = fmaxf(mx, rowpart[((size_t)zz * 16 + nh) * L_ + l]);
        float g = 1.0f / (1.0f + __expf(-(w0 * p * (1.0f / S_) + w1 * mx + bb)));
        out[(((size_t)n * L_ + l) * H_ + h) * D_ + lane] = q * qm * g;
    }
}

extern "C" void kernel_launch(void* const* d_in, const int* in_sizes, int n_in,
                              void* d_out, int out_size, void* d_ws, size_t ws_size,
                              hipStream_t stream) {
    const float* Q      = (const float*)d_in[0];
    const float* K      = (const float*)d_in[1];
    // d_in[2] = values: masked in reference but unused downstream
    const float* qmask  = (const float*)d_in[3];
    const float* kvmask = (const float*)d_in[4];
    const float* W      = (const float*)d_in[5];
    const float* b      = (const float*)d_in[6];
    float* out = (float*)d_out;

    float* Kpart   = (float*)d_ws;                    // 32*16*64 f = 128 KB
    float* rowpart = (float*)d_ws + KP * 16 * 64;     // 8*16*2048 f = 1 MB

    ksum_kernel<<<dim3(N_ * H_, S_ / 64), 256, 0, stream>>>(K, kvmask, Kpart);
    rowmax_mfma<<<dim3((L_ / BLK_L) * (N_ * H_) * SSPLIT), 256, 0, stream>>>(
        Q, K, qmask, kvmask, rowpart);
    finalize_kernel<<<dim3(L_ / 64, N_ * H_), 256, 0, stream>>>(
        Q, qmask, Kpart, rowpart, W, b, out);
}

// Round 6
// 130.288 us; speedup vs baseline: 1.3504x; 1.3504x over previous
//
#include <hip/hip_runtime.h>
#include <math.h>

#define N_ 2
#define L_ 2048
#define S_ 2048
#define H_ 8
#define D_ 64

#define BLK_L 256        // l-rows per block (4 waves x 64)
#define BS 64            // s-rows per K tile
#define SSPLIT 8
#define TILES (S_ / SSPLIT / BS)   // 4
#define KROW 80          // LDS row stride in shorts (160B): uniform 32-bank spread
#define KP 32            // ksum partial slices (S/64)

typedef __attribute__((ext_vector_type(8))) short short8;
typedef __attribute__((ext_vector_type(4))) float floatx4;

__device__ __forceinline__ float feat(float x) {
    // elu(x)+1 = x>0 ? x+1 : exp(x)
    return x > 0.0f ? x + 1.0f : __expf(x);
}
__device__ __forceinline__ short f2bf(float x) {
    unsigned u = __float_as_uint(x);
    unsigned r = (u + 0x7fffu + ((u >> 16) & 1u)) >> 16;   // round-nearest-even
    return (short)r;
}
__device__ __forceinline__ float bf2f(short h) {
    return __uint_as_float(((unsigned)(unsigned short)h) << 16);
}

// ---- K feature-sum partials (no atomics, no memset) ----
__global__ __launch_bounds__(256) void ksum_kernel(const float* __restrict__ K,
        const float* __restrict__ kvmask, float* __restrict__ Kpart) {
    int nh = blockIdx.x;          // 16
    int sc = blockIdx.y;          // 32 chunks of 64 s-rows
    int n = nh >> 3, h = nh & 7;
    int t = threadIdx.x;
    int sr = t >> 4;              // 0..15
    int d4 = (t & 15) * 4;
    float sums[4] = {0.f, 0.f, 0.f, 0.f};
    #pragma unroll
    for (int p = 0; p < 4; ++p) {
        int s = sc * 64 + p * 16 + sr;
        float km = kvmask[n * S_ + s];
        float4 v = *(const float4*)(K + (((size_t)n * S_ + s) * H_ + h) * D_ + d4);
        sums[0] += feat(v.x) * km; sums[1] += feat(v.y) * km;
        sums[2] += feat(v.z) * km; sums[3] += feat(v.w) * km;
    }
    __shared__ float smf[16][64];
    #pragma unroll
    for (int j = 0; j < 4; ++j) smf[sr][d4 + j] = sums[j];
    __syncthreads();
    if (t < 64) {
        float s = 0.f;
        #pragma unroll
        for (int r = 0; r < 16; ++r) s += smf[r][t];
        Kpart[(sc * 16 + nh) * 64 + t] = s;
    }
}

// ---- fused row-max: featurize K in-kernel, compensated-bf16 MFMA ----
// grid (x=ltile, y=nh, z=zsplit): consecutive ids share the K slice (R3-measured
// full K L2 reuse: 8.4 MB fetched). Single LDS buffer, loads issued pre-barrier.
__global__ __launch_bounds__(256, 4) void rowmax_mfma(
        const float* __restrict__ Q, const float* __restrict__ K,
        const float* __restrict__ qmask, const float* __restrict__ kvmask,
        float* __restrict__ rowpart) {
    __shared__ short Kh[BS * KROW];
    __shared__ short Kl[BS * KROW];

    int ltile = blockIdx.x;
    int nh = blockIdx.y;
    int z = blockIdx.z;
    int n = nh >> 3, h = nh & 7;
    int t = threadIdx.x;
    int w = t >> 6, lane = t & 63;
    int quad = lane >> 4, l16 = lane & 15;
    int lblock = ltile * BLK_L;

    // ---- prologue: featurize Q -> A fragments in registers (hi/lo bf16) ----
    // A-frag layout (16x16x32): m = lane&15, k = quad*8 + j
    short8 Ah[4][2], Al[4][2];
    #pragma unroll
    for (int lsub = 0; lsub < 4; ++lsub) {
        int lrow = lblock + w * 64 + lsub * 16 + l16;
        float qm = qmask[n * L_ + lrow];
        const float* qp = Q + (((size_t)n * L_ + lrow) * H_ + h) * D_ + quad * 8;
        #pragma unroll
        for (int ks = 0; ks < 2; ++ks) {
            float4 v0 = *(const float4*)(qp + ks * 32);
            float4 v1 = *(const float4*)(qp + ks * 32 + 4);
            float fv[8];
            fv[0] = feat(v0.x) * qm; fv[1] = feat(v0.y) * qm;
            fv[2] = feat(v0.z) * qm; fv[3] = feat(v0.w) * qm;
            fv[4] = feat(v1.x) * qm; fv[5] = feat(v1.y) * qm;
            fv[6] = feat(v1.z) * qm; fv[7] = feat(v1.w) * qm;
            short8 hi, lo;
            #pragma unroll
            for (int j = 0; j < 8; ++j) {
                short hb = f2bf(fv[j]);
                hi[j] = hb;
                lo[j] = f2bf(fv[j] - bf2f(hb));
            }
            Ah[lsub][ks] = hi;
            Al[lsub][ks] = lo;
        }
    }

    float rmax[4][4];
    #pragma unroll
    for (int i = 0; i < 4; ++i)
        #pragma unroll
        for (int r = 0; r < 4; ++r) rmax[i][r] = 0.f;   // dots >= 0

    for (int tile = 0; tile < TILES; ++tile) {
        int sbase = z * (S_ / SSPLIT) + tile * BS;

        // issue global loads BEFORE the barrier: latency overlaps barrier wait
        // staging map: id in {t, t+256}; s = id>>3, granule g = id&7
        // LDS dword addr 40s+4g -> all 32 banks uniformly (R4: 0 conflicts)
        float4 gv[2][2];
        float gkm[2];
        #pragma unroll
        for (int p = 0; p < 2; ++p) {
            int id = t + 256 * p;
            int s = id >> 3, g = id & 7;
            const float* kp = K + (((size_t)n * S_ + sbase + s) * H_ + h) * D_ + g * 8;
            gv[p][0] = *(const float4*)(kp);
            gv[p][1] = *(const float4*)(kp + 4);
            gkm[p] = kvmask[n * S_ + sbase + s];
        }

        __syncthreads();   // previous tile's LDS reads complete

        #pragma unroll
        for (int p = 0; p < 2; ++p) {
            int id = t + 256 * p;
            int s = id >> 3, g = id & 7;
            float fv[8];
            fv[0] = feat(gv[p][0].x) * gkm[p]; fv[1] = feat(gv[p][0].y) * gkm[p];
            fv[2] = feat(gv[p][0].z) * gkm[p]; fv[3] = feat(gv[p][0].w) * gkm[p];
            fv[4] = feat(gv[p][1].x) * gkm[p]; fv[5] = feat(gv[p][1].y) * gkm[p];
            fv[6] = feat(gv[p][1].z) * gkm[p]; fv[7] = feat(gv[p][1].w) * gkm[p];
            short8 hi, lo;
            #pragma unroll
            for (int j = 0; j < 8; ++j) {
                short hb = f2bf(fv[j]);
                hi[j] = hb;
                lo[j] = f2bf(fv[j] - bf2f(hb));
            }
            *(short8*)(&Kh[s * KROW + g * 8]) = hi;
            *(short8*)(&Kl[s * KROW + g * 8]) = lo;
        }

        __syncthreads();   // tile visible

        #pragma unroll
        for (int ssub = 0; ssub < 4; ++ssub) {
            // B-frag: n = lane&15 (s-row), k = quad*8 + j
            const short* bph = &Kh[(ssub * 16 + l16) * KROW + quad * 8];
            const short* bpl = &Kl[(ssub * 16 + l16) * KROW + quad * 8];
            short8 Bh0 = *(const short8*)(bph);
            short8 Bh1 = *(const short8*)(bph + 32);
            short8 Bl0 = *(const short8*)(bpl);
            short8 Bl1 = *(const short8*)(bpl + 32);
            #pragma unroll
            for (int lsub = 0; lsub < 4; ++lsub) {
                floatx4 acc = {0.f, 0.f, 0.f, 0.f};
                acc = __builtin_amdgcn_mfma_f32_16x16x32_bf16(Ah[lsub][0], Bh0, acc, 0, 0, 0);
                acc = __builtin_amdgcn_mfma_f32_16x16x32_bf16(Ah[lsub][1], Bh1, acc, 0, 0, 0);
                acc = __builtin_amdgcn_mfma_f32_16x16x32_bf16(Ah[lsub][0], Bl0, acc, 0, 0, 0);
                acc = __builtin_amdgcn_mfma_f32_16x16x32_bf16(Ah[lsub][1], Bl1, acc, 0, 0, 0);
                acc = __builtin_amdgcn_mfma_f32_16x16x32_bf16(Al[lsub][0], Bh0, acc, 0, 0, 0);
                acc = __builtin_amdgcn_mfma_f32_16x16x32_bf16(Al[lsub][1], Bh1, acc, 0, 0, 0);
                #pragma unroll
                for (int r = 0; r < 4; ++r)
                    rmax[lsub][r] = fmaxf(rmax[lsub][r], acc[r]);
            }
        }
    }

    // ---- epilogue: reduce across 16 column-lanes, write z-partial ----
    // C/D layout: col(s) = lane&15, row(l) = quad*4 + r
    #pragma unroll
    for (int lsub = 0; lsub < 4; ++lsub)
        #pragma unroll
        for (int r = 0; r < 4; ++r) {
            float m = rmax[lsub][r];
            m = fmaxf(m, __shfl_xor(m, 1, 64));
            m = fmaxf(m, __shfl_xor(m, 2, 64));
            m = fmaxf(m, __shfl_xor(m, 4, 64));
            m = fmaxf(m, __shfl_xor(m, 8, 64));
            if (l16 == 0) {
                int l = lblock + w * 64 + lsub * 16 + quad * 4 + r;
                rowpart[((size_t)z * 16 + nh) * L_ + l] = m;
            }
        }
}

// ---- finalize: Ksum reduce + mean + max + gate + masked write ----
__global__ __launch_bounds__(256) void finalize_kernel(
        const float* __restrict__ Q, const float* __restrict__ qmask,
        const float* __restrict__ Kpart, const float* __restrict__ rowpart,
        const float* __restrict__ W, const float* __restrict__ b,
        float* __restrict__ out) {
    int nh = blockIdx.y;
    int n = nh >> 3, h = nh & 7;
    int lblock = blockIdx.x * 64;
    int t = threadIdx.x;
    int w = t >> 6, lane = t & 63;

    float ks = 0.f;
    #pragma unroll 8
    for (int p = 0; p < KP; ++p)
        ks += Kpart[(p * 16 + nh) * 64 + lane];

    float w0 = W[0], w1 = W[1], bb = b[0];

    #pragma unroll 4
    for (int r = 0; r < 16; ++r) {
        int l = lblock + w * 16 + r;
        float q = Q[(((size_t)n * L_ + l) * H_ + h) * D_ + lane];
        float qm = qmask[n * L_ + l];
        float p = feat(q) * qm * ks;
        #pragma unroll
        for (int off = 32; off > 0; off >>= 1)
            p += __shfl_xor(p, off, 64);
        float mx = 0.f;
        #pragma unroll
        for (int zz = 0; zz < SSPLIT; ++zz)
            mx = fmaxf(mx, rowpart[((size_t)zz * 16 + nh) * L_ + l]);
        float g = 1.0f / (1.0f + __expf(-(w0 * p * (1.0f / S_) + w1 * mx + bb)));
        out[(((size_t)n * L_ + l) * H_ + h) * D_ + lane] = q * qm * g;
    }
}

extern "C" void kernel_launch(void* const* d_in, const int* in_sizes, int n_in,
                              void* d_out, int out_size, void* d_ws, size_t ws_size,
                              hipStream_t stream) {
    const float* Q      = (const float*)d_in[0];
    const float* K      = (const float*)d_in[1];
    // d_in[2] = values: masked in reference but unused downstream
    const float* qmask  = (const float*)d_in[3];
    const float* kvmask = (const float*)d_in[4];
    const float* W      = (const float*)d_in[5];
    const float* b      = (const float*)d_in[6];
    float* out = (float*)d_out;

    float* Kpart   = (float*)d_ws;                    // 32*16*64 f = 128 KB
    float* rowpart = (float*)d_ws + KP * 16 * 64;     // 8*16*2048 f = 1 MB

    ksum_kernel<<<dim3(N_ * H_, S_ / 64), 256, 0, stream>>>(K, kvmask, Kpart);
    rowmax_mfma<<<dim3(L_ / BLK_L, N_ * H_, SSPLIT), 256, 0, stream>>>(
        Q, K, qmask, kvmask, rowpart);
    finalize_kernel<<<dim3(L_ / 64, N_ * H_), 256, 0, stream>>>(
        Q, qmask, Kpart, rowpart, W, b, out);
}